// Round 1
// 2177.900 us; speedup vs baseline: 2.0502x; 2.0502x over previous
//
#include <hip/hip_runtime.h>
#include <math.h>

#define T_TOK 16384
#define D_DIM 1024
#define E_EXP 48
#define S_SH 4
#define M_DIM 1024
#define N1 4096      // S*M
#define K_OUT 256    // D/S
#define CAP 512

typedef __attribute__((ext_vector_type(8))) short bf16x8;
typedef __attribute__((ext_vector_type(4))) float f32x4;

__device__ inline unsigned f2ord(float f) {
  unsigned u = __float_as_uint(f);
  return (u & 0x80000000u) ? ~u : (u | 0x80000000u);
}

__device__ inline unsigned short f2bf(float f) {
  unsigned u = __float_as_uint(f);
  unsigned r = (u + 0x7fffu + ((u >> 16) & 1u)) >> 16;
  return (unsigned short)r;
}
__device__ inline float bf2f(unsigned short h) {
  return __uint_as_float(((unsigned)h) << 16);
}
__device__ inline float gelu_exact(float v) {
  return 0.5f * v * (1.0f + erff(v * 0.7071067811865476f));
}

// async global->LDS, 16B per lane; LDS dest = wave-uniform base + lane*16
__device__ __forceinline__ void gl2lds16(const void* g, void* l) {
  __builtin_amdgcn_global_load_lds(
      (const __attribute__((address_space(1))) unsigned int*)g,
      (__attribute__((address_space(3))) unsigned int*)l, 16, 0, 0);
}

// ---------------- Router: logitsT[E][T] = (x @ Wr^T)^T, fp64 accumulate ---------
// kept in fp64 so top-k SELECTION matches the JAX fp32 reference bit-stably.
__global__ __launch_bounds__(256) void router_kernel(
    const float* __restrict__ x, const float* __restrict__ Wr,
    float* __restrict__ logitsT) {
  __shared__ float xs[32][129];
  __shared__ float wsh[48][129];
  int t0 = blockIdx.x * 32;
  int tid = threadIdx.x;
  double acc[6];
#pragma unroll
  for (int q = 0; q < 6; q++) acc[q] = 0.0;
  for (int d0 = 0; d0 < D_DIM; d0 += 128) {
    for (int i = tid; i < 32 * 128; i += 256)
      xs[i >> 7][i & 127] = x[(size_t)(t0 + (i >> 7)) * D_DIM + d0 + (i & 127)];
    for (int i = tid; i < 48 * 128; i += 256)
      wsh[i >> 7][i & 127] = Wr[(size_t)(i >> 7) * D_DIM + d0 + (i & 127)];
    __syncthreads();
#pragma unroll
    for (int q = 0; q < 6; q++) {
      int p = tid + 256 * q;
      int t = p & 31, e = p >> 5;
      double a = 0.0;
      for (int d = 0; d < 128; d++) a += (double)xs[t][d] * (double)wsh[e][d];
      acc[q] += a;
    }
    __syncthreads();
  }
  for (int q = 0; q < 6; q++) {
    int p = tid + 256 * q;
    int t = p & 31, e = p >> 5;
    logitsT[(size_t)e * T_TOK + t0 + t] = (float)acc[q];
  }
}

// ---------------- Top-512 per expert (radix select) + softmax -------------------
__global__ __launch_bounds__(256) void topk_kernel(
    const float* __restrict__ logitsT, int* __restrict__ idx_sel,
    float* __restrict__ w_sel) {
  int e = blockIdx.x;
  const float* lg = logitsT + (size_t)e * T_TOK;
  __shared__ unsigned hist[256];
  __shared__ unsigned sh_prefix;
  __shared__ int sh_kneed;
  __shared__ int cnt_gt, cnt_eq;
  __shared__ int eq_idx[256];
  __shared__ float red[256];
  int tid = threadIdx.x;
  unsigned prefix = 0;
  int kneed = CAP;
  for (int shift = 24; shift >= 0; shift -= 8) {
    hist[tid] = 0;
    __syncthreads();
    for (int t = tid; t < T_TOK; t += 256) {
      unsigned u = f2ord(lg[t]);
      bool ok = (shift == 24) || ((u >> (shift + 8)) == prefix);
      if (ok) atomicAdd(&hist[(u >> shift) & 255u], 1u);
    }
    __syncthreads();
    if (tid == 0) {
      int k = kneed;
      unsigned b = 255;
      for (;; b--) {
        int c = (int)hist[b];
        if (k <= c || b == 0) break;
        k -= c;
      }
      sh_prefix = (prefix << 8) | b;
      sh_kneed = k;
      cnt_gt = 0;
      cnt_eq = 0;
    }
    __syncthreads();
    prefix = sh_prefix;
    kneed = sh_kneed;
    __syncthreads();
  }
  unsigned pivot = prefix;
  for (int t = tid; t < T_TOK; t += 256) {
    unsigned u = f2ord(lg[t]);
    if (u > pivot) {
      int p = atomicAdd(&cnt_gt, 1);
      idx_sel[e * CAP + p] = t;
    } else if (u == pivot) {
      int p = atomicAdd(&cnt_eq, 1);
      if (p < 256) eq_idx[p] = t;
    }
  }
  __syncthreads();
  if (tid == 0) {
    int base = cnt_gt;
    int ne = cnt_eq < 256 ? cnt_eq : 256;
    for (int s = 0; s < kneed; s++) {
      int best = 0x7fffffff, bj = -1;
      for (int j = 0; j < ne; j++) {
        int v = eq_idx[j];
        if (v >= 0 && v < best) { best = v; bj = j; }
      }
      if (bj >= 0) eq_idx[bj] = -1; else best = 0;
      idx_sel[e * CAP + base + s] = best;
    }
  }
  __syncthreads();
  float vmax = -INFINITY;
  for (int s = tid; s < CAP; s += 256) vmax = fmaxf(vmax, lg[idx_sel[e * CAP + s]]);
  red[tid] = vmax;
  __syncthreads();
  for (int o = 128; o > 0; o >>= 1) {
    if (tid < o) red[tid] = fmaxf(red[tid], red[tid + o]);
    __syncthreads();
  }
  vmax = red[0];
  __syncthreads();
  float lsum = 0.f;
  for (int s = tid; s < CAP; s += 256) lsum += expf(lg[idx_sel[e * CAP + s]] - vmax);
  red[tid] = lsum;
  __syncthreads();
  for (int o = 128; o > 0; o >>= 1) {
    if (tid < o) red[tid] += red[tid + o];
    __syncthreads();
  }
  float denom = red[0];
  for (int s = tid; s < CAP; s += 256)
    w_sel[e * CAP + s] = expf(lg[idx_sel[e * CAP + s]] - vmax) / denom;
}

// ---------------- Gather + split x into bf16 hi/lo, PRE-SWIZZLED ---------------
// Layout: within each 64-elem k-segment, 8-elem chunk q stored at (q ^ (c&7)).
// This makes a LINEAR global_load_lds produce a bank-conflict-free swizzled tile.
__global__ __launch_bounds__(128) void gather_kernel(
    const float* __restrict__ x, const int* __restrict__ idx_sel,
    unsigned short* __restrict__ Xh, unsigned short* __restrict__ Xl, int e0) {
  int b = blockIdx.x;
  int eL = b >> 9, c = b & 511;
  int tok = idx_sel[(e0 + eL) * CAP + c];
  int k = threadIdx.x << 3;
  const float* xp = x + ((size_t)tok << 10) + k;
  float4 v0 = *(const float4*)xp;
  float4 v1 = *(const float4*)(xp + 4);
  float f[8] = {v0.x, v0.y, v0.z, v0.w, v1.x, v1.y, v1.z, v1.w};
  bf16x8 h8, l8;
#pragma unroll
  for (int i = 0; i < 8; i++) {
    unsigned short h = f2bf(f[i]);
    h8[i] = (short)h;
    l8[i] = (short)f2bf(f[i] - bf2f(h));
  }
  int q = (k >> 3) & 7;
  size_t dst = (((size_t)(eL << 9) + (size_t)c) << 10) + (size_t)((k & ~63) + ((q ^ (c & 7)) << 3));
  *(bf16x8*)(Xh + dst) = h8;
  *(bf16x8*)(Xl + dst) = l8;
}

// ---------------- GEMM1: H = gelu(Xg @ W1 + b1), split-bf16 3-pass MFMA --------
// per expert: [512 x 1024] @ [1024 x 4096]; 128x128 tiles, BK=64, 4 waves.
__global__ __launch_bounds__(256, 2) void gemm1_mfma(
    const unsigned short* __restrict__ Xh, const unsigned short* __restrict__ Xl,
    const float* __restrict__ W1, const float* __restrict__ b1,
    unsigned short* __restrict__ H, int e0) {
  __shared__ alignas(16) unsigned short Ah[128 * 64];
  __shared__ alignas(16) unsigned short Al[128 * 64];
  __shared__ alignas(16) unsigned short Bh[128 * 64];
  __shared__ alignas(16) unsigned short Bl[128 * 64];
  int bid = blockIdx.x;
  int eL = bid >> 7;
  int rem = bid & 127;
  int nt = rem >> 2, ct = rem & 3;  // ct-inner: 4 consecutive blocks share W1 n-slab
  int e = e0 + eL;
  int n0 = nt << 7;
  int s = n0 >> 10, m0 = n0 & 1023;
  int c0 = ct << 7;
  int tid = threadIdx.x;
  int lane = tid & 63, wid = tid >> 6;
  int wr = wid >> 1, wc = wid & 1;
  int lr = lane & 15, lq = lane >> 4;
  int qn = tid & 31, ko = tid >> 5;
  const float* W1p = W1 + (((size_t)(e * S_SH + s)) << 20);
  const unsigned short* Xhp = Xh + ((((size_t)eL << 9) + (size_t)c0) << 10);
  const unsigned short* Xlp = Xl + ((((size_t)eL << 9) + (size_t)c0) << 10);
  f32x4 acc[4][4];
#pragma unroll
  for (int i = 0; i < 4; i++)
#pragma unroll
    for (int j = 0; j < 4; j++) acc[i][j] = f32x4{0.f, 0.f, 0.f, 0.f};

  float4 wv[8], wn[8];
#pragma unroll
  for (int i = 0; i < 8; i++)
    wv[i] = *(const float4*)(W1p + (((size_t)(ko * 8 + i)) << 10) + m0 + (qn << 2));

  for (int k0 = 0; k0 < D_DIM; k0 += 64) {
    // A: async DMA global->LDS (layout pre-swizzled in Xg, linear copy)
#pragma unroll
    for (int i = 0; i < 4; i++) {
      int rb = wid * 32 + i * 8;
      int r = rb + (lane >> 3);
      gl2lds16(Xhp + (((size_t)r) << 10) + k0 + ((lane & 7) << 3), &Ah[rb * 64]);
    }
#pragma unroll
    for (int i = 0; i < 4; i++) {
      int rb = wid * 32 + i * 8;
      int r = rb + (lane >> 3);
      gl2lds16(Xlp + (((size_t)r) << 10) + k0 + ((lane & 7) << 3), &Al[rb * 64]);
    }
    // B: fp32 -> bf16 hi/lo, transposed swizzled LDS write (b128)
#pragma unroll
    for (int j = 0; j < 4; j++) {
      bf16x8 h8, l8;
#pragma unroll
      for (int i = 0; i < 8; i++) {
        float f = ((const float*)&wv[i])[j];
        unsigned short h = f2bf(f);
        h8[i] = (short)h;
        l8[i] = (short)f2bf(f - bf2f(h));
      }
      int nl = (qn << 2) + j;
      int ch = ko ^ ((nl >> 1) & 7);
      *(bf16x8*)&Bh[nl * 64 + ch * 8] = h8;
      *(bf16x8*)&Bl[nl * 64 + ch * 8] = l8;
    }
    __syncthreads();
    // prefetch next W1 tile during MFMA phase (drained by the NEXT barrier)
    if (k0 + 64 < D_DIM) {
#pragma unroll
      for (int i = 0; i < 8; i++)
        wn[i] = *(const float4*)(W1p + (((size_t)(k0 + 64 + ko * 8 + i)) << 10) + m0 + (qn << 2));
    }
#pragma unroll
    for (int ks = 0; ks < 2; ks++) {
      bf16x8 afh[4], afl[4], bfh[4], bfl[4];
#pragma unroll
      for (int mi = 0; mi < 4; mi++) {
        int r = wr * 64 + mi * 16 + lr;
        int ch = (ks * 4 + lq) ^ (r & 7);
        afh[mi] = *(const bf16x8*)&Ah[r * 64 + ch * 8];
        afl[mi] = *(const bf16x8*)&Al[r * 64 + ch * 8];
      }
#pragma unroll
      for (int ni = 0; ni < 4; ni++) {
        int n = wc * 64 + ni * 16 + lr;
        int ch = (ks * 4 + lq) ^ ((n >> 1) & 7);
        bfh[ni] = *(const bf16x8*)&Bh[n * 64 + ch * 8];
        bfl[ni] = *(const bf16x8*)&Bl[n * 64 + ch * 8];
      }
#pragma unroll
      for (int mi = 0; mi < 4; mi++)
#pragma unroll
        for (int ni = 0; ni < 4; ni++) {
          acc[mi][ni] = __builtin_amdgcn_mfma_f32_16x16x32_bf16(afh[mi], bfh[ni], acc[mi][ni], 0, 0, 0);
          acc[mi][ni] = __builtin_amdgcn_mfma_f32_16x16x32_bf16(afh[mi], bfl[ni], acc[mi][ni], 0, 0, 0);
          acc[mi][ni] = __builtin_amdgcn_mfma_f32_16x16x32_bf16(afl[mi], bfh[ni], acc[mi][ni], 0, 0, 0);
        }
    }
    __syncthreads();
#pragma unroll
    for (int i = 0; i < 8; i++) wv[i] = wn[i];
  }
  // epilogue: bias + gelu + bf16 store, H stored with same XOR swizzle (bits 3..5)
  const float* b1p = b1 + ((size_t)(e * S_SH + s)) * M_DIM + m0;
#pragma unroll
  for (int ni = 0; ni < 4; ni++) {
    int col_t = wc * 64 + ni * 16 + lr;
    float bb = b1p[col_t];
    int nglob = n0 + col_t;
#pragma unroll
    for (int mi = 0; mi < 4; mi++) {
      f32x4 a = acc[mi][ni];
#pragma unroll
      for (int j = 0; j < 4; j++) {
        int row = c0 + wr * 64 + mi * 16 + lq * 4 + j;  // C/D: col=l&15, row=(l>>4)*4+reg
        int nsw = nglob ^ ((row & 7) << 3);
        H[(((size_t)(eL * CAP + row)) << 12) + nsw] = f2bf(gelu_exact(a[j] + bb));
      }
    }
  }
}

// ---------------- GEMM2: y = H @ W2 + b2, 2-pass MFMA, weighted scatter --------
// per (e,s): [512 x 1024] @ [1024 x 256]; 128x128 tiles, BK=64.
__global__ __launch_bounds__(256, 2) void gemm2_mfma(
    const unsigned short* __restrict__ H, const float* __restrict__ W2,
    const float* __restrict__ b2, const int* __restrict__ idx_sel,
    const float* __restrict__ w_sel, float* __restrict__ out, int e0) {
  __shared__ alignas(16) unsigned short Ah[128 * 64];
  __shared__ alignas(16) unsigned short Bh[128 * 64];
  __shared__ alignas(16) unsigned short Bl[128 * 64];
  __shared__ int toks[128];
  __shared__ float wts[128];
  int bid = blockIdx.x;
  int eL = bid >> 5;
  int rem = bid & 31;
  int s = rem >> 3;
  int r2 = rem & 7;
  int nt = r2 >> 2, ct = r2 & 3;
  int e = e0 + eL;
  int n0 = nt << 7;
  int c0 = ct << 7;
  int tid = threadIdx.x;
  int lane = tid & 63, wid = tid >> 6;
  int wr = wid >> 1, wc = wid & 1;
  int lr = lane & 15, lq = lane >> 4;
  int qn = tid & 31, ko = tid >> 5;
  if (tid < 128) {
    toks[tid] = idx_sel[e * CAP + c0 + tid];
    wts[tid] = w_sel[e * CAP + c0 + tid];
  }
  const float* W2p = W2 + (((size_t)(e * S_SH + s)) << 18);
  const unsigned short* Hp = H + ((((size_t)(eL * CAP + c0)) << 12) + ((size_t)s << 10));
  f32x4 acc[4][4];
#pragma unroll
  for (int i = 0; i < 4; i++)
#pragma unroll
    for (int j = 0; j < 4; j++) acc[i][j] = f32x4{0.f, 0.f, 0.f, 0.f};

  float4 wv[8], wn[8];
#pragma unroll
  for (int i = 0; i < 8; i++)
    wv[i] = *(const float4*)(W2p + (((size_t)(ko * 8 + i)) << 8) + n0 + (qn << 2));

  for (int k0 = 0; k0 < M_DIM; k0 += 64) {
#pragma unroll
    for (int i = 0; i < 4; i++) {
      int rb = wid * 32 + i * 8;
      int r = rb + (lane >> 3);
      gl2lds16(Hp + (((size_t)r) << 12) + k0 + ((lane & 7) << 3), &Ah[rb * 64]);
    }
#pragma unroll
    for (int j = 0; j < 4; j++) {
      bf16x8 h8, l8;
#pragma unroll
      for (int i = 0; i < 8; i++) {
        float f = ((const float*)&wv[i])[j];
        unsigned short h = f2bf(f);
        h8[i] = (short)h;
        l8[i] = (short)f2bf(f - bf2f(h));
      }
      int nl = (qn << 2) + j;
      int ch = ko ^ ((nl >> 1) & 7);
      *(bf16x8*)&Bh[nl * 64 + ch * 8] = h8;
      *(bf16x8*)&Bl[nl * 64 + ch * 8] = l8;
    }
    __syncthreads();
    if (k0 + 64 < M_DIM) {
#pragma unroll
      for (int i = 0; i < 8; i++)
        wn[i] = *(const float4*)(W2p + (((size_t)(k0 + 64 + ko * 8 + i)) << 8) + n0 + (qn << 2));
    }
#pragma unroll
    for (int ks = 0; ks < 2; ks++) {
      bf16x8 afh[4], bfh[4], bfl[4];
#pragma unroll
      for (int mi = 0; mi < 4; mi++) {
        int r = wr * 64 + mi * 16 + lr;
        int ch = (ks * 4 + lq) ^ (r & 7);
        afh[mi] = *(const bf16x8*)&Ah[r * 64 + ch * 8];
      }
#pragma unroll
      for (int ni = 0; ni < 4; ni++) {
        int n = wc * 64 + ni * 16 + lr;
        int ch = (ks * 4 + lq) ^ ((n >> 1) & 7);
        bfh[ni] = *(const bf16x8*)&Bh[n * 64 + ch * 8];
        bfl[ni] = *(const bf16x8*)&Bl[n * 64 + ch * 8];
      }
#pragma unroll
      for (int mi = 0; mi < 4; mi++)
#pragma unroll
        for (int ni = 0; ni < 4; ni++) {
          acc[mi][ni] = __builtin_amdgcn_mfma_f32_16x16x32_bf16(afh[mi], bfh[ni], acc[mi][ni], 0, 0, 0);
          acc[mi][ni] = __builtin_amdgcn_mfma_f32_16x16x32_bf16(afh[mi], bfl[ni], acc[mi][ni], 0, 0, 0);
        }
    }
    __syncthreads();
#pragma unroll
    for (int i = 0; i < 8; i++) wv[i] = wn[i];
  }
  const float* b2p = b2 + ((size_t)(e * S_SH + s)) * K_OUT + n0;
#pragma unroll
  for (int ni = 0; ni < 4; ni++) {
    int col_t = wc * 64 + ni * 16 + lr;
    float bb = b2p[col_t];
    int ocol = (s << 8) + n0 + col_t;
#pragma unroll
    for (int mi = 0; mi < 4; mi++) {
      f32x4 a = acc[mi][ni];
#pragma unroll
      for (int j = 0; j < 4; j++) {
        int rloc = wr * 64 + mi * 16 + lq * 4 + j;
        int tok = toks[rloc];
        float wt = wts[rloc];
        unsafeAtomicAdd(out + ((size_t)tok << 10) + ocol, (a[j] + bb) * wt);
      }
    }
  }
}

extern "C" void kernel_launch(void* const* d_in, const int* in_sizes, int n_in,
                              void* d_out, int out_size, void* d_ws, size_t ws_size,
                              hipStream_t stream) {
  const float* x = (const float*)d_in[0];
  const float* Wr = (const float*)d_in[1];
  const float* W1 = (const float*)d_in[2];
  const float* b1 = (const float*)d_in[3];
  const float* W2 = (const float*)d_in[4];
  const float* b2 = (const float*)d_in[5];
  float* out = (float*)d_out;

  char* wsb = (char*)d_ws;
  float* logitsT = (float*)wsb;                      // 48*16384*4 = 3,145,728 B
  int* idx_sel = (int*)(wsb + 3145728);              // 48*512*4   =    98,304 B
  float* w_sel = (float*)(wsb + 3244032);            // 48*512*4   =    98,304 B
  unsigned short* Xh = (unsigned short*)(wsb + 3342336);
  size_t per_e_x = (size_t)CAP * D_DIM;              // elements (1 MiB bytes each of hi/lo)
  size_t per_e_h = (size_t)CAP * N1;                 // elements (4 MiB bytes)
  long long per_e_bytes = (long long)(per_e_x * 4 + per_e_h * 2);  // 6,291,456
  long long avail = (long long)ws_size - 3342336LL;
  int chunk = (int)(avail / per_e_bytes);
  if (chunk < 1) chunk = 1;
  if (chunk > E_EXP) chunk = E_EXP;
  unsigned short* Xl = Xh + (size_t)chunk * per_e_x;
  unsigned short* Hbuf = Xl + (size_t)chunk * per_e_x;

  hipMemsetAsync(d_out, 0, (size_t)T_TOK * D_DIM * sizeof(float), stream);
  router_kernel<<<T_TOK / 32, 256, 0, stream>>>(x, Wr, logitsT);
  topk_kernel<<<E_EXP, 256, 0, stream>>>(logitsT, idx_sel, w_sel);
  for (int ee = 0; ee < E_EXP; ee += chunk) {
    int ne = (chunk < E_EXP - ee) ? chunk : (E_EXP - ee);
    gather_kernel<<<ne * 512, 128, 0, stream>>>(x, idx_sel, Xh, Xl, ee);
    gemm1_mfma<<<ne * 128, 256, 0, stream>>>(Xh, Xl, W1, b1, Hbuf, ee);
    gemm2_mfma<<<ne * 32, 256, 0, stream>>>(Hbuf, W2, b2, idx_sel, w_sel, out, ee);
  }
}